// Round 2
// baseline (203.190 us; speedup 1.0000x reference)
//
#include <hip/hip_runtime.h>

// Involution: B=4, C=256, H=W=56, K=7, GC=16 -> G=16, Cr=64, K2=49
// ws layout: mid [4][64][3136] fp32 (3.21 MB). w2 is never materialized:
// conv2 + apply are fused per (b, 4-group chunk, 8x8 spatial tile) block.

#define EPS 1e-5f

// ---------------- Kernel 1: conv1 (1x1, 256->64) + BN + ReLU ----------------
// tile 64o x 64px, K chunks of 64; thread-tile 8o x 2px, float4-over-c w reads.
__global__ __launch_bounds__(256) void k1_conv1(
    const float* __restrict__ x, const float* __restrict__ w1,
    const float* __restrict__ gamma, const float* __restrict__ beta,
    const float* __restrict__ mean, const float* __restrict__ var,
    float* __restrict__ mid)
{
    __shared__ float lx[64 * 64];                  // [c][px]
    __shared__ __align__(16) float lw[64 * 64];    // [o][c], c contiguous
    const int t  = threadIdx.x;
    const int b  = blockIdx.y;
    const int p0 = blockIdx.x * 64;
    const int pxA = t & 31, pxB = pxA + 32;
    const int ob  = (t >> 5) * 8;                  // 8 outputs per thread
    float acc[8][2];
#pragma unroll
    for (int i = 0; i < 8; ++i) { acc[i][0] = 0.f; acc[i][1] = 0.f; }

    for (int c0 = 0; c0 < 256; c0 += 64) {
#pragma unroll
        for (int i = 0; i < 16; ++i) {
            int idx = t + i * 256;
            lx[idx] = x[(b * 256 + c0 + (idx >> 6)) * 3136 + p0 + (idx & 63)];
            lw[idx] = w1[(idx >> 6) * 256 + c0 + (idx & 63)];
        }
        __syncthreads();
        for (int cc = 0; cc < 64; cc += 4) {
            float xa[4], xb[4];
#pragma unroll
            for (int q = 0; q < 4; ++q) {
                xa[q] = lx[(cc + q) * 64 + pxA];
                xb[q] = lx[(cc + q) * 64 + pxB];
            }
#pragma unroll
            for (int i = 0; i < 8; ++i) {
                const float4 wv = *(const float4*)&lw[(ob + i) * 64 + cc];
                acc[i][0] = fmaf(wv.x, xa[0], acc[i][0]);
                acc[i][0] = fmaf(wv.y, xa[1], acc[i][0]);
                acc[i][0] = fmaf(wv.z, xa[2], acc[i][0]);
                acc[i][0] = fmaf(wv.w, xa[3], acc[i][0]);
                acc[i][1] = fmaf(wv.x, xb[0], acc[i][1]);
                acc[i][1] = fmaf(wv.y, xb[1], acc[i][1]);
                acc[i][1] = fmaf(wv.z, xb[2], acc[i][1]);
                acc[i][1] = fmaf(wv.w, xb[3], acc[i][1]);
            }
        }
        __syncthreads();
    }
#pragma unroll
    for (int i = 0; i < 8; ++i) {
        int o = ob + i;
        float s   = gamma[o] * rsqrtf(var[o] + EPS);
        float off = beta[o] - mean[o] * s;
        mid[(b * 64 + o) * 3136 + p0 + pxA] = fmaxf(fmaf(acc[i][0], s, off), 0.f);
        mid[(b * 64 + o) * 3136 + p0 + pxB] = fmaxf(fmaf(acc[i][1], s, off), 0.f);
    }
}

// ---------------- Kernel 2: fused conv2 + unfold/apply ----------------------
// block = (b, 4 groups, 8x8 tile). Per group: GEMM w2[k][px] (k padded to 64)
// from LDS mid-tile and cw-slice, store to LDS, then sliding-window apply.
__global__ __launch_bounds__(256, 2) void k23_fused(
    const float* __restrict__ x, const float* __restrict__ mid,
    const float* __restrict__ cw, const float* __restrict__ cb,
    float* __restrict__ out)
{
    __shared__ __align__(16) float lmid[64 * 64];  // [c][px], px = sh*8+sw
    __shared__ float lw[64 * 65];                  // [k][c] +1 pad (rows 49..63 unused)
    __shared__ __align__(16) float lw2[49 * 64];   // [k][px]
    __shared__ float lx[16 * 196];                 // [ch][14x14 halo]
    const int t  = threadIdx.x;
    const int b  = blockIdx.z;
    const int g0 = blockIdx.y * 4;
    const int th = blockIdx.x / 7, tw = blockIdx.x % 7;
    const int h0 = th * 8, w0 = tw * 8;

    // stage mid tile [c][px] (reused by all 4 groups)
#pragma unroll
    for (int i = 0; i < 16; ++i) {
        int idx = t + i * 256;
        int c = idx >> 6, px = idx & 63;
        lmid[idx] = mid[(b * 64 + c) * 3136 + (h0 + (px >> 3)) * 56 + w0 + (px & 7)];
    }

    const int kt = t >> 4, pxt = t & 15;
    const int k4 = kt * 4, px4 = pxt * 4;
    const int cc = t >> 4, pxg = t & 15;
    const int sh = pxg >> 1, sw4 = (pxg & 1) * 4;

    for (int gi = 0; gi < 4; ++gi) {
        const int g = g0 + gi;
        __syncthreads();   // prev iter's readers done (also covers lmid staging)
        for (int idx = t; idx < 49 * 64; idx += 256)
            lw[(idx >> 6) * 65 + (idx & 63)] = cw[(g * 49 + (idx >> 6)) * 64 + (idx & 63)];
        for (int idx = t; idx < 16 * 196; idx += 256) {
            int ch = idx / 196, r = idx % 196;
            int rr = r / 14, col = r % 14;
            int gh = h0 + rr - 3, gw = w0 + col - 3;
            float v = 0.f;
            if (gh >= 0 && gh < 56 && gw >= 0 && gw < 56)
                v = x[(b * 256 + g * 16 + ch) * 3136 + gh * 56 + gw];
            lx[idx] = v;
        }
        __syncthreads();

        // GEMM: 64k x 64px x 64c, thread-tile 4k x 4px
        float acc[4][4];
#pragma unroll
        for (int i = 0; i < 4; ++i)
#pragma unroll
            for (int j = 0; j < 4; ++j) acc[i][j] = 0.f;
        for (int c = 0; c < 64; ++c) {
            const float4 m = *(const float4*)&lmid[c * 64 + px4];
#pragma unroll
            for (int i = 0; i < 4; ++i) {
                const float w = lw[(k4 + i) * 65 + c];
                acc[i][0] = fmaf(w, m.x, acc[i][0]);
                acc[i][1] = fmaf(w, m.y, acc[i][1]);
                acc[i][2] = fmaf(w, m.z, acc[i][2]);
                acc[i][3] = fmaf(w, m.w, acc[i][3]);
            }
        }
#pragma unroll
        for (int i = 0; i < 4; ++i) {
            int k = k4 + i;
            if (k < 49) {
                float bias = cb[g * 49 + k];
                *(float4*)&lw2[k * 64 + px4] = make_float4(
                    acc[i][0] + bias, acc[i][1] + bias,
                    acc[i][2] + bias, acc[i][3] + bias);
            }
        }
        __syncthreads();

        // apply: thread = (cc, 4 consecutive out px); sliding x row in regs
        float a0 = 0.f, a1 = 0.f, a2 = 0.f, a3 = 0.f;
#pragma unroll
        for (int kh = 0; kh < 7; ++kh) {
            float xr[10];
#pragma unroll
            for (int j = 0; j < 10; ++j)
                xr[j] = lx[cc * 196 + (sh + kh) * 14 + sw4 + j];
#pragma unroll
            for (int kw = 0; kw < 7; ++kw) {
                const float4 wv = *(const float4*)&lw2[(kh * 7 + kw) * 64 + px4];
                a0 = fmaf(wv.x, xr[kw + 0], a0);
                a1 = fmaf(wv.y, xr[kw + 1], a1);
                a2 = fmaf(wv.z, xr[kw + 2], a2);
                a3 = fmaf(wv.w, xr[kw + 3], a3);
            }
        }
        *(float4*)&out[(b * 256 + g * 16 + cc) * 3136 + (h0 + sh) * 56 + w0 + sw4] =
            make_float4(a0, a1, a2, a3);
    }
}

extern "C" void kernel_launch(void* const* d_in, const int* in_sizes, int n_in,
                              void* d_out, int out_size, void* d_ws, size_t ws_size,
                              hipStream_t stream) {
    const float* x     = (const float*)d_in[0];
    const float* w1    = (const float*)d_in[1];
    const float* gamma = (const float*)d_in[2];
    const float* beta  = (const float*)d_in[3];
    const float* mean  = (const float*)d_in[4];
    const float* var   = (const float*)d_in[5];
    const float* cw    = (const float*)d_in[6];
    const float* cb    = (const float*)d_in[7];
    float* out = (float*)d_out;

    float* mid = (float*)d_ws;   // 4*64*3136 floats

    k1_conv1<<<dim3(49, 4), 256, 0, stream>>>(x, w1, gamma, beta, mean, var, mid);
    k23_fused<<<dim3(49, 4, 4), 256, 0, stream>>>(x, mid, cw, cb, out);
}

// Round 4
// 135.908 us; speedup vs baseline: 1.4951x; 1.4951x over previous
//
#include <hip/hip_runtime.h>

// Involution: B=4, C=256, H=W=56, K=7, GC=16 -> G=16, Cr=64, K2=49
// ws: mid[4*64*3136] | w1f[256c][64o] (BN-folded, transposed) | b1f[64] |
//     cwT[16g][64c][64k] (k padded 49->64 with zeros)
// k0: build w1f/b1f/cwT. k1: conv1 GEMM (64o x 64px tiles, grid 49x4).
// k23: fused conv2 GEMM + unfold/apply per (b,g,8x8 tile), 3136 blocks.
// All LDS weight layouts are [c][out] stride-64: b128 reads at 4*group
// dwords -> 2-way bank aliasing (free). Staging is contiguous float4.

#define EPS 1e-5f

// ---------------- Kernel 0: weight prep ----------------
__global__ __launch_bounds__(256) void k0_setup(
    const float* __restrict__ w1, const float* __restrict__ gamma,
    const float* __restrict__ beta, const float* __restrict__ mean,
    const float* __restrict__ var, const float* __restrict__ cw,
    float* __restrict__ w1f, float* __restrict__ b1f, float* __restrict__ cwT)
{
    const int tid = blockIdx.x * 256 + threadIdx.x;
    const int nthr = gridDim.x * 256;
    for (int idx = tid; idx < 16384; idx += nthr) {          // w1f[c][o]
        int c = idx >> 6, o = idx & 63;
        float s = gamma[o] * rsqrtf(var[o] + EPS);
        w1f[idx] = w1[o * 256 + c] * s;
    }
    for (int idx = tid; idx < 64; idx += nthr) {             // b1f[o]
        float s = gamma[idx] * rsqrtf(var[idx] + EPS);
        b1f[idx] = beta[idx] - mean[idx] * s;
    }
    for (int idx = tid; idx < 65536; idx += nthr) {          // cwT[g][c][k]
        int g = idx >> 12, c = (idx >> 6) & 63, k = idx & 63;
        cwT[idx] = (k < 49) ? cw[(g * 49 + k) * 64 + c] : 0.f;
    }
}

// ---------------- Kernel 1: conv1 (1x1, 256->64) + BN + ReLU ----------------
// grid (49, 4): block tile 64o x 64px, thread tile 4o x 4px, K chunks of 64.
__global__ __launch_bounds__(256) void k1_conv1(
    const float* __restrict__ x, const float* __restrict__ w1f,
    const float* __restrict__ b1f, float* __restrict__ mid)
{
    __shared__ __align__(16) float lx[64 * 64];   // [c][px]
    __shared__ __align__(16) float lw[64 * 64];   // [c][o]
    const int t   = threadIdx.x;
    const int b   = blockIdx.y;
    const int p0  = blockIdx.x * 64;
    const int o4  = (t >> 4) * 4;
    const int px4 = (t & 15) * 4;
    float acc[4][4] = {};

    for (int c0 = 0; c0 < 256; c0 += 64) {
#pragma unroll
        for (int i = 0; i < 4; ++i) {
            int s  = t + i * 256;                  // 1024 float4 slots
            int r  = s >> 4, q4 = (s & 15) * 4;
            *(float4*)&lx[r * 64 + q4] =
                *(const float4*)&x[(b * 256 + c0 + r) * 3136 + p0 + q4];
            *(float4*)&lw[s * 4] = *(const float4*)&w1f[c0 * 64 + s * 4];
        }
        __syncthreads();
#pragma unroll 4
        for (int c = 0; c < 64; c += 4) {
            float4 mv[4], wv[4];
#pragma unroll
            for (int q = 0; q < 4; ++q) {
                mv[q] = *(const float4*)&lx[(c + q) * 64 + px4];
                wv[q] = *(const float4*)&lw[(c + q) * 64 + o4];
            }
            const float* mf = (const float*)mv;    // mf[q*4+j]
            const float* wf = (const float*)wv;    // wf[q*4+i]
#pragma unroll
            for (int q = 0; q < 4; ++q)
#pragma unroll
                for (int i = 0; i < 4; ++i) {
                    float wiq = wf[q * 4 + i];
#pragma unroll
                    for (int j = 0; j < 4; ++j)
                        acc[i][j] = fmaf(wiq, mf[q * 4 + j], acc[i][j]);
                }
        }
        __syncthreads();
    }
#pragma unroll
    for (int i = 0; i < 4; ++i) {
        float bb = b1f[o4 + i];
        float4 v = make_float4(
            fmaxf(acc[i][0] + bb, 0.f), fmaxf(acc[i][1] + bb, 0.f),
            fmaxf(acc[i][2] + bb, 0.f), fmaxf(acc[i][3] + bb, 0.f));
        *(float4*)&mid[(b * 64 + o4 + i) * 3136 + p0 + px4] = v;
    }
}

// ---------------- Kernel 2: fused conv2 + unfold/apply ----------------------
__global__ __launch_bounds__(256, 3) void k23_fused(
    const float* __restrict__ x, const float* __restrict__ mid,
    const float* __restrict__ cwT, const float* __restrict__ cb,
    float* __restrict__ out)
{
    // lmid[64c][64px] | lwk[64c][64k] (lx[16ch][196] overlays) | lw2[49k][64px]
    __shared__ __align__(16) float smem[4096 + 4096 + 3136];
    float* lmid = smem;
    float* lwk  = smem + 4096;
    float* lx   = smem + 4096;           // overlays lwk after GEMM
    float* lw2  = smem + 8192;

    const int t  = threadIdx.x;
    const int b  = blockIdx.z;
    const int g  = blockIdx.y;
    const int th = blockIdx.x / 7, tw = blockIdx.x % 7;
    const int h0 = th * 8, w0 = tw * 8;

    // stage lmid [c][px], px = sh*8+sw
#pragma unroll
    for (int i = 0; i < 4; ++i) {
        int s  = t + i * 256;
        int c  = s >> 4, pf = s & 15;
        int sh = pf >> 1, sw4 = (pf & 1) * 4;
        *(float4*)&lmid[c * 64 + pf * 4] =
            *(const float4*)&mid[(b * 64 + c) * 3136 + (h0 + sh) * 56 + w0 + sw4];
    }
    // stage lwk [c][k] — contiguous copy from cwT
#pragma unroll
    for (int i = 0; i < 4; ++i) {
        int s = t + i * 256;
        *(float4*)&lwk[s * 4] = *(const float4*)&cwT[g * 4096 + s * 4];
    }
    // prefetch x halo (16ch x 14x14 = 3136) into registers
    float rv[13];
#pragma unroll
    for (int i = 0; i < 13; ++i) {
        int idx = t + i * 256;
        float v = 0.f;
        if (idx < 3136) {
            int ch = idx / 196, r = idx % 196;
            int rr = r / 14, col = r % 14;
            int gh = h0 + rr - 3, gw = w0 + col - 3;
            if (gh >= 0 && gh < 56 && gw >= 0 && gw < 56)
                v = x[(b * 256 + g * 16 + ch) * 3136 + gh * 56 + gw];
        }
        rv[i] = v;
    }
    __syncthreads();

    // GEMM: w2[k][px] = cb + sum_c cwT[c][k]*lmid[c][px]; thread tile 4k x 4px
    const int kt = t >> 4, pxt = t & 15;
    const int k4 = kt * 4, px4 = pxt * 4;
    float acc[4][4] = {};
#pragma unroll 4
    for (int c = 0; c < 64; c += 4) {
        float4 mv[4], wv[4];
#pragma unroll
        for (int q = 0; q < 4; ++q) {
            mv[q] = *(const float4*)&lmid[(c + q) * 64 + px4];
            wv[q] = *(const float4*)&lwk[(c + q) * 64 + k4];
        }
        const float* mf = (const float*)mv;
        const float* wf = (const float*)wv;
#pragma unroll
        for (int q = 0; q < 4; ++q)
#pragma unroll
            for (int i = 0; i < 4; ++i) {
                float wiq = wf[q * 4 + i];
#pragma unroll
                for (int j = 0; j < 4; ++j)
                    acc[i][j] = fmaf(wiq, mf[q * 4 + j], acc[i][j]);
            }
    }
#pragma unroll
    for (int i = 0; i < 4; ++i) {
        int k = k4 + i;
        if (k < 49) {
            float bias = cb[g * 49 + k];
            *(float4*)&lw2[k * 64 + px4] = make_float4(
                acc[i][0] + bias, acc[i][1] + bias,
                acc[i][2] + bias, acc[i][3] + bias);
        }
    }
    __syncthreads();

    // halo regs -> LDS (contiguous, stride 196 per channel)
#pragma unroll
    for (int i = 0; i < 13; ++i) {
        int idx = t + i * 256;
        if (idx < 3136) lx[idx] = rv[i];
    }
    __syncthreads();

    // apply: thread = (cc, 4 consecutive out px)
    const int cc = kt, pxg = pxt;
    const int sh = pxg >> 1, sw4 = (pxg & 1) * 4;
    float a0 = 0.f, a1 = 0.f, a2 = 0.f, a3 = 0.f;
#pragma unroll
    for (int kh = 0; kh < 7; ++kh) {
        float xr[10];
        const int base = cc * 196 + (sh + kh) * 14 + sw4;
#pragma unroll
        for (int j = 0; j < 10; ++j) xr[j] = lx[base + j];
#pragma unroll
        for (int kw = 0; kw < 7; ++kw) {
            const float4 wv = *(const float4*)&lw2[(kh * 7 + kw) * 64 + px4];
            a0 = fmaf(wv.x, xr[kw + 0], a0);
            a1 = fmaf(wv.y, xr[kw + 1], a1);
            a2 = fmaf(wv.z, xr[kw + 2], a2);
            a3 = fmaf(wv.w, xr[kw + 3], a3);
        }
    }
    *(float4*)&out[(b * 256 + g * 16 + cc) * 3136 + (h0 + sh) * 56 + w0 + sw4] =
        make_float4(a0, a1, a2, a3);
}

extern "C" void kernel_launch(void* const* d_in, const int* in_sizes, int n_in,
                              void* d_out, int out_size, void* d_ws, size_t ws_size,
                              hipStream_t stream) {
    const float* x     = (const float*)d_in[0];
    const float* w1    = (const float*)d_in[1];
    const float* gamma = (const float*)d_in[2];
    const float* beta  = (const float*)d_in[3];
    const float* mean  = (const float*)d_in[4];
    const float* var   = (const float*)d_in[5];
    const float* cw    = (const float*)d_in[6];
    const float* cb    = (const float*)d_in[7];
    float* out = (float*)d_out;

    float* mid = (float*)d_ws;            // 802816 floats
    float* w1f = mid + 802816;            // 16384
    float* b1f = w1f + 16384;             // 64
    float* cwT = b1f + 64;                // 65536

    k0_setup<<<dim3(64), 256, 0, stream>>>(w1, gamma, beta, mean, var, cw,
                                           w1f, b1f, cwT);
    k1_conv1<<<dim3(49, 4), 256, 0, stream>>>(x, w1f, b1f, mid);
    k23_fused<<<dim3(49, 16, 4), 256, 0, stream>>>(x, mid, cwT, cb, out);
}

// Round 6
// 125.856 us; speedup vs baseline: 1.6145x; 1.0799x over previous
//
#include <hip/hip_runtime.h>

// Involution: B=4, C=256, H=W=56, K=7, GC=16 -> G=16, Cr=64, K2=49
// f16 internal pipeline: GEMMs use v_dot2_f32_f16 (f16 mul, fp32 acc).
// ws (bytes): mid f16 [4][3136 p][64 c]            @ 0        (1605632 B)
//             w1fh f16 [128 c2][64 o][2] BN-folded @ 1605632  (32768 B)
//             b1f  f32 [64]                        @ 1638400  (256 B)
//             cwb  f16 [16 g][32 c2][64 k][2]      @ 1638656  (131072 B)
// k23: per (b,g,8x8 tile): f16 GEMM -> lw2 (fp32) -> fp32 apply (unchanged).

#define EPS 1e-5f

typedef __fp16 half2t __attribute__((ext_vector_type(2)));
typedef __fp16 half4t __attribute__((ext_vector_type(4)));
typedef __fp16 half8t __attribute__((ext_vector_type(8)));

// ---------------- Kernel 0: weight prep (fp32 -> f16 layouts) ----------------
__global__ __launch_bounds__(256) void k0_setup(
    const float* __restrict__ w1, const float* __restrict__ gamma,
    const float* __restrict__ beta, const float* __restrict__ mean,
    const float* __restrict__ var, const float* __restrict__ cw,
    __fp16* __restrict__ w1fh, float* __restrict__ b1f,
    __fp16* __restrict__ cwb)
{
    const int tid = blockIdx.x * 256 + threadIdx.x;
    const int n   = gridDim.x * 256;
    for (int idx = tid; idx < 16384; idx += n) {        // w1fh[c2][o][2]
        int c2 = idx >> 7, r = idx & 127, o = r >> 1, c = 2 * c2 + (r & 1);
        float s = gamma[o] * rsqrtf(var[o] + EPS);
        w1fh[idx] = (__fp16)(w1[o * 256 + c] * s);
    }
    for (int idx = tid; idx < 64; idx += n) {           // b1f[o]
        float s = gamma[idx] * rsqrtf(var[idx] + EPS);
        b1f[idx] = beta[idx] - mean[idx] * s;
    }
    for (int idx = tid; idx < 65536; idx += n) {        // cwb[g][c2][k][2]
        int g = idx >> 12, r = idx & 4095;
        int c2 = r >> 7, r2 = r & 127, k = r2 >> 1, c = 2 * c2 + (r2 & 1);
        cwb[idx] = (__fp16)((k < 49) ? cw[(g * 49 + k) * 64 + c] : 0.f);
    }
}

// ---------------- Kernel 1: conv1 (1x1, 256->64) + BN + ReLU ----------------
// grid (49,4): tile 64o x 64px, K=256 in 4 chunks, thread tile 4o x 4px, dot2.
__global__ __launch_bounds__(256, 4) void k1_conv1(
    const float* __restrict__ x, const __fp16* __restrict__ w1fh,
    const float* __restrict__ b1f, __fp16* __restrict__ mid)
{
    __shared__ __align__(16) __fp16 lx2[32 * 136];   // [c2][64px][2], pad->136
    __shared__ __align__(16) __fp16 lwh[32 * 128];   // [c2][64o][2]
    const int t   = threadIdx.x;
    const int b   = blockIdx.y;
    const int p0  = blockIdx.x * 64;
    const int o4  = (t >> 4) * 4;
    const int px4 = (t & 15) * 4;
    float acc[4][4] = {};

    for (int c0 = 0; c0 < 256; c0 += 64) {
        // stage x chunk: thread = (c2 pair of rows, 8 px); pack pairs via pkrtz
        {
            int c2 = t >> 3, px8 = (t & 7) * 8;
            const float* r0 = &x[(size_t)(b * 256 + c0 + 2 * c2) * 3136 + p0 + px8];
            const float* r1 = r0 + 3136;
            float4 a0 = *(const float4*)r0, a1 = *(const float4*)(r0 + 4);
            float4 b0 = *(const float4*)r1, b1 = *(const float4*)(r1 + 4);
            half8t lo, hi;
            half2t q;
            q = __builtin_amdgcn_cvt_pkrtz(a0.x, b0.x); lo[0]=q[0]; lo[1]=q[1];
            q = __builtin_amdgcn_cvt_pkrtz(a0.y, b0.y); lo[2]=q[0]; lo[3]=q[1];
            q = __builtin_amdgcn_cvt_pkrtz(a0.z, b0.z); lo[4]=q[0]; lo[5]=q[1];
            q = __builtin_amdgcn_cvt_pkrtz(a0.w, b0.w); lo[6]=q[0]; lo[7]=q[1];
            q = __builtin_amdgcn_cvt_pkrtz(a1.x, b1.x); hi[0]=q[0]; hi[1]=q[1];
            q = __builtin_amdgcn_cvt_pkrtz(a1.y, b1.y); hi[2]=q[0]; hi[3]=q[1];
            q = __builtin_amdgcn_cvt_pkrtz(a1.z, b1.z); hi[4]=q[0]; hi[5]=q[1];
            q = __builtin_amdgcn_cvt_pkrtz(a1.w, b1.w); hi[6]=q[0]; hi[7]=q[1];
            *(half8t*)&lx2[c2 * 136 + px8 * 2]     = lo;
            *(half8t*)&lx2[c2 * 136 + px8 * 2 + 8] = hi;
        }
        // stage w chunk (contiguous copy)
#pragma unroll
        for (int i = 0; i < 2; ++i) {
            int s = t + i * 256;
            *(half8t*)&lwh[s * 8] = *(const half8t*)&w1fh[c0 * 64 + s * 8];
        }
        __syncthreads();
#pragma unroll 4
        for (int c2 = 0; c2 < 32; ++c2) {
            half8t mv = *(const half8t*)&lx2[c2 * 136 + px4 * 2];
            half8t wv = *(const half8t*)&lwh[c2 * 128 + o4 * 2];
            half2t mp[4], wp[4];
#pragma unroll
            for (int j = 0; j < 4; ++j) {
                mp[j][0] = mv[2 * j]; mp[j][1] = mv[2 * j + 1];
                wp[j][0] = wv[2 * j]; wp[j][1] = wv[2 * j + 1];
            }
#pragma unroll
            for (int i = 0; i < 4; ++i)
#pragma unroll
                for (int j = 0; j < 4; ++j)
                    acc[i][j] = __builtin_amdgcn_fdot2(wp[i], mp[j], acc[i][j], false);
        }
        __syncthreads();
    }
    float bb[4];
#pragma unroll
    for (int i = 0; i < 4; ++i) bb[i] = b1f[o4 + i];
#pragma unroll
    for (int j = 0; j < 4; ++j) {
        int p = p0 + px4 + j;
        float v0 = fmaxf(acc[0][j] + bb[0], 0.f);
        float v1 = fmaxf(acc[1][j] + bb[1], 0.f);
        float v2 = fmaxf(acc[2][j] + bb[2], 0.f);
        float v3 = fmaxf(acc[3][j] + bb[3], 0.f);
        half2t u0 = __builtin_amdgcn_cvt_pkrtz(v0, v1);
        half2t u1 = __builtin_amdgcn_cvt_pkrtz(v2, v3);
        half4t h; h[0] = u0[0]; h[1] = u0[1]; h[2] = u1[0]; h[3] = u1[1];
        *(half4t*)&mid[(size_t)(b * 3136 + p) * 64 + o4] = h;
    }
}

// ---------------- Kernel 2: fused conv2 (f16 dot2) + unfold/apply (fp32) ----
__global__ __launch_bounds__(256, 5) void k23_fused(
    const float* __restrict__ x, const __fp16* __restrict__ mid,
    const __fp16* __restrict__ cwb, const float* __restrict__ cb,
    float* __restrict__ out)
{
    __shared__ __align__(16) unsigned char smem[28928];
    __fp16* lmid2 = (__fp16*)smem;               // [32 c2][64 px][2] 8192 B
    __fp16* lwk2  = (__fp16*)(smem + 8192);      // [32 c2][64 k][2]  8192 B
    float*  lx    = (float*)smem;                // overlays after GEMM (12544 B)
    float*  lw2   = (float*)(smem + 16384);      // [49][64] fp32    12544 B

    const int t  = threadIdx.x;
    const int b  = blockIdx.z;
    const int g  = blockIdx.y;
    const int th = blockIdx.x / 7, tw = blockIdx.x % 7;
    const int h0 = th * 8, w0 = tw * 8;

    // stage lmid2: pairs come adjacent in mid's [p][c] rows
#pragma unroll
    for (int i = 0; i < 2; ++i) {
        int s  = t + i * 256;
        int px = s & 63, c8 = s >> 6;
        int pix = (h0 + (px >> 3)) * 56 + w0 + (px & 7);
        half8t v = *(const half8t*)&mid[(size_t)(b * 3136 + pix) * 64 + c8 * 8];
#pragma unroll
        for (int q = 0; q < 4; ++q) {
            half2t p; p[0] = v[2 * q]; p[1] = v[2 * q + 1];
            *(half2t*)&lmid2[(c8 * 4 + q) * 128 + px * 2] = p;
        }
    }
    // stage lwk2 (contiguous copy)
#pragma unroll
    for (int i = 0; i < 2; ++i) {
        int s = t + i * 256;
        *(half8t*)&lwk2[s * 8] = *(const half8t*)&cwb[g * 4096 + s * 8];
    }
    // prefetch x halo (16ch x 14x14 = 3136) into registers
    float rv[13];
#pragma unroll
    for (int i = 0; i < 13; ++i) {
        int idx = t + i * 256;
        float v = 0.f;
        if (idx < 3136) {
            int ch = idx / 196, r = idx % 196;
            int rr = r / 14, col = r % 14;
            int gh = h0 + rr - 3, gw = w0 + col - 3;
            if (gh >= 0 && gh < 56 && gw >= 0 && gw < 56)
                v = x[(b * 256 + g * 16 + ch) * 3136 + gh * 56 + gw];
        }
        rv[i] = v;
    }
    __syncthreads();

    // GEMM: w2[k][px] = cb + sum_c cwb(c,k)*mid(c,px); thread tile 4k x 4px
    const int kt = t >> 4, pxt = t & 15;
    const int k4 = kt * 4, px4 = pxt * 4;
    float acc[4][4] = {};
#pragma unroll 4
    for (int c2 = 0; c2 < 32; ++c2) {
        half8t mv = *(const half8t*)&lmid2[c2 * 128 + px4 * 2];
        half8t wv = *(const half8t*)&lwk2[c2 * 128 + k4 * 2];
        half2t mp[4], wp[4];
#pragma unroll
        for (int j = 0; j < 4; ++j) {
            mp[j][0] = mv[2 * j]; mp[j][1] = mv[2 * j + 1];
            wp[j][0] = wv[2 * j]; wp[j][1] = wv[2 * j + 1];
        }
#pragma unroll
        for (int i = 0; i < 4; ++i)
#pragma unroll
            for (int j = 0; j < 4; ++j)
                acc[i][j] = __builtin_amdgcn_fdot2(wp[i], mp[j], acc[i][j], false);
    }
#pragma unroll
    for (int i = 0; i < 4; ++i) {
        int k = k4 + i;
        if (k < 49) {
            float bias = cb[g * 49 + k];
            *(float4*)&lw2[k * 64 + px4] = make_float4(
                acc[i][0] + bias, acc[i][1] + bias,
                acc[i][2] + bias, acc[i][3] + bias);
        }
    }
    __syncthreads();

    // halo regs -> LDS (contiguous, stride 196 per channel)
#pragma unroll
    for (int i = 0; i < 13; ++i) {
        int idx = t + i * 256;
        if (idx < 3136) lx[idx] = rv[i];
    }
    __syncthreads();

    // apply: thread = (cc, 4 consecutive out px), fp32
    const int cc = kt, pxg = pxt;
    const int sh = pxg >> 1, sw4 = (pxg & 1) * 4;
    float a0 = 0.f, a1 = 0.f, a2 = 0.f, a3 = 0.f;
#pragma unroll
    for (int kh = 0; kh < 7; ++kh) {
        float xr[10];
        const int base = cc * 196 + (sh + kh) * 14 + sw4;
#pragma unroll
        for (int j = 0; j < 10; ++j) xr[j] = lx[base + j];
#pragma unroll
        for (int kw = 0; kw < 7; ++kw) {
            const float4 wv = *(const float4*)&lw2[(kh * 7 + kw) * 64 + px4];
            a0 = fmaf(wv.x, xr[kw + 0], a0);
            a1 = fmaf(wv.y, xr[kw + 1], a1);
            a2 = fmaf(wv.z, xr[kw + 2], a2);
            a3 = fmaf(wv.w, xr[kw + 3], a3);
        }
    }
    *(float4*)&out[(b * 256 + g * 16 + cc) * 3136 + (h0 + sh) * 56 + w0 + sw4] =
        make_float4(a0, a1, a2, a3);
}

extern "C" void kernel_launch(void* const* d_in, const int* in_sizes, int n_in,
                              void* d_out, int out_size, void* d_ws, size_t ws_size,
                              hipStream_t stream) {
    const float* x     = (const float*)d_in[0];
    const float* w1    = (const float*)d_in[1];
    const float* gamma = (const float*)d_in[2];
    const float* beta  = (const float*)d_in[3];
    const float* mean  = (const float*)d_in[4];
    const float* var   = (const float*)d_in[5];
    const float* cw    = (const float*)d_in[6];
    const float* cb    = (const float*)d_in[7];
    float* out = (float*)d_out;

    unsigned char* ws = (unsigned char*)d_ws;
    __fp16* mid  = (__fp16*)(ws);             // 1605632 B
    __fp16* w1fh = (__fp16*)(ws + 1605632);   // 32768 B
    float*  b1f  = (float*)(ws + 1638400);    // 256 B
    __fp16* cwb  = (__fp16*)(ws + 1638656);   // 131072 B

    k0_setup<<<dim3(64), 256, 0, stream>>>(w1, gamma, beta, mean, var, cw,
                                           w1fh, b1f, cwb);
    k1_conv1<<<dim3(49, 4), 256, 0, stream>>>(x, w1fh, b1f, mid);
    k23_fused<<<dim3(49, 16, 4), 256, 0, stream>>>(x, mid, cwb, cb, out);
}

// Round 7
// 113.470 us; speedup vs baseline: 1.7907x; 1.1092x over previous
//
#include <hip/hip_runtime.h>

// Involution: B=4, C=256, H=W=56, K=7, GC=16 -> G=16, Cr=64, K2=49
// conv1: f16 dot2 GEMM. conv2: f16 MFMA (16x16x32) fused with fp32 apply.
// ws: mid f16 [4][3136 p][64 c] @0 | w1fh f16 [128 c2][64 o][2] @1605632 |
//     b1f f32[64] @1638400 | cwb f16 [16 g][64 k][64 c] @1638656
// k23 LDS: lmid[64px][72] f16 | lwk[64k][72] f16 (lx[16ch][232] f32 overlays
// both after GEMM; row stride 15, ch stride 232 => 2-way banks in apply) |
// lw2[49][68] f32 (stride 68 => 2-way C-stores, b128 apply reads).

#define EPS 1e-5f

typedef __fp16 half2t __attribute__((ext_vector_type(2)));
typedef __fp16 half4t __attribute__((ext_vector_type(4)));
typedef __fp16 half8t __attribute__((ext_vector_type(8)));
typedef float floatx4 __attribute__((ext_vector_type(4)));

// ---------------- Kernel 0: weight prep ----------------
__global__ __launch_bounds__(256) void k0_setup(
    const float* __restrict__ w1, const float* __restrict__ gamma,
    const float* __restrict__ beta, const float* __restrict__ mean,
    const float* __restrict__ var, const float* __restrict__ cw,
    __fp16* __restrict__ w1fh, float* __restrict__ b1f,
    __fp16* __restrict__ cwb)
{
    const int tid = blockIdx.x * 256 + threadIdx.x;
    const int n   = gridDim.x * 256;
    for (int idx = tid; idx < 16384; idx += n) {        // w1fh[c2][o][2]
        int c2 = idx >> 7, r = idx & 127, o = r >> 1, c = 2 * c2 + (r & 1);
        float s = gamma[o] * rsqrtf(var[o] + EPS);
        w1fh[idx] = (__fp16)(w1[o * 256 + c] * s);
    }
    for (int idx = tid; idx < 64; idx += n) {           // b1f[o]
        float s = gamma[idx] * rsqrtf(var[idx] + EPS);
        b1f[idx] = beta[idx] - mean[idx] * s;
    }
    for (int idx = tid; idx < 65536; idx += n) {        // cwb[g][k][c]
        int g = idx >> 12, k = (idx >> 6) & 63, c = idx & 63;
        cwb[idx] = (__fp16)((k < 49) ? cw[(g * 49 + k) * 64 + c] : 0.f);
    }
}

// ---------------- Kernel 1: conv1 (1x1, 256->64) + BN + ReLU ----------------
__global__ __launch_bounds__(256, 4) void k1_conv1(
    const float* __restrict__ x, const __fp16* __restrict__ w1fh,
    const float* __restrict__ b1f, __fp16* __restrict__ mid)
{
    __shared__ __align__(16) __fp16 lx2[32 * 136];   // [c2][64px][2], pad->136
    __shared__ __align__(16) __fp16 lwh[32 * 128];   // [c2][64o][2]
    const int t   = threadIdx.x;
    const int b   = blockIdx.y;
    const int p0  = blockIdx.x * 64;
    const int o4  = (t >> 4) * 4;
    const int px4 = (t & 15) * 4;
    float acc[4][4] = {};

    for (int c0 = 0; c0 < 256; c0 += 64) {
        {
            int c2 = t >> 3, px8 = (t & 7) * 8;
            const float* r0 = &x[(size_t)(b * 256 + c0 + 2 * c2) * 3136 + p0 + px8];
            const float* r1 = r0 + 3136;
            float4 a0 = *(const float4*)r0, a1 = *(const float4*)(r0 + 4);
            float4 b0 = *(const float4*)r1, b1 = *(const float4*)(r1 + 4);
            half8t lo, hi;
            half2t q;
            q = __builtin_amdgcn_cvt_pkrtz(a0.x, b0.x); lo[0]=q[0]; lo[1]=q[1];
            q = __builtin_amdgcn_cvt_pkrtz(a0.y, b0.y); lo[2]=q[0]; lo[3]=q[1];
            q = __builtin_amdgcn_cvt_pkrtz(a0.z, b0.z); lo[4]=q[0]; lo[5]=q[1];
            q = __builtin_amdgcn_cvt_pkrtz(a0.w, b0.w); lo[6]=q[0]; lo[7]=q[1];
            q = __builtin_amdgcn_cvt_pkrtz(a1.x, b1.x); hi[0]=q[0]; hi[1]=q[1];
            q = __builtin_amdgcn_cvt_pkrtz(a1.y, b1.y); hi[2]=q[0]; hi[3]=q[1];
            q = __builtin_amdgcn_cvt_pkrtz(a1.z, b1.z); hi[4]=q[0]; hi[5]=q[1];
            q = __builtin_amdgcn_cvt_pkrtz(a1.w, b1.w); hi[6]=q[0]; hi[7]=q[1];
            *(half8t*)&lx2[c2 * 136 + px8 * 2]     = lo;
            *(half8t*)&lx2[c2 * 136 + px8 * 2 + 8] = hi;
        }
#pragma unroll
        for (int i = 0; i < 2; ++i) {
            int s = t + i * 256;
            *(half8t*)&lwh[s * 8] = *(const half8t*)&w1fh[c0 * 64 + s * 8];
        }
        __syncthreads();
#pragma unroll 4
        for (int c2 = 0; c2 < 32; ++c2) {
            half8t mv = *(const half8t*)&lx2[c2 * 136 + px4 * 2];
            half8t wv = *(const half8t*)&lwh[c2 * 128 + o4 * 2];
            half2t mp[4], wp[4];
#pragma unroll
            for (int j = 0; j < 4; ++j) {
                mp[j][0] = mv[2 * j]; mp[j][1] = mv[2 * j + 1];
                wp[j][0] = wv[2 * j]; wp[j][1] = wv[2 * j + 1];
            }
#pragma unroll
            for (int i = 0; i < 4; ++i)
#pragma unroll
                for (int j = 0; j < 4; ++j)
                    acc[i][j] = __builtin_amdgcn_fdot2(wp[i], mp[j], acc[i][j], false);
        }
        __syncthreads();
    }
    float bb[4];
#pragma unroll
    for (int i = 0; i < 4; ++i) bb[i] = b1f[o4 + i];
#pragma unroll
    for (int j = 0; j < 4; ++j) {
        int p = p0 + px4 + j;
        float v0 = fmaxf(acc[0][j] + bb[0], 0.f);
        float v1 = fmaxf(acc[1][j] + bb[1], 0.f);
        float v2 = fmaxf(acc[2][j] + bb[2], 0.f);
        float v3 = fmaxf(acc[3][j] + bb[3], 0.f);
        half2t u0 = __builtin_amdgcn_cvt_pkrtz(v0, v1);
        half2t u1 = __builtin_amdgcn_cvt_pkrtz(v2, v3);
        half4t h; h[0] = u0[0]; h[1] = u0[1]; h[2] = u1[0]; h[3] = u1[1];
        *(half4t*)&mid[(size_t)(b * 3136 + p) * 64 + o4] = h;
    }
}

// ---------------- Kernel 2: fused conv2 (f16 MFMA) + unfold/apply (fp32) ----
__global__ __launch_bounds__(256, 5) void k23_fused(
    const float* __restrict__ x, const __fp16* __restrict__ mid,
    const __fp16* __restrict__ cwb, const float* __restrict__ cb,
    float* __restrict__ out)
{
    __shared__ __align__(16) unsigned char smem[31760];
    __fp16* lmid = (__fp16*)smem;                // [64 px][72] 9216 B
    __fp16* lwk  = (__fp16*)(smem + 9216);       // [64 ko][72] 9216 B
    float*  lx   = (float*)smem;                 // [16 ch][232] 14848 B overlay
    float*  lw2  = (float*)(smem + 18432);       // [49][68] 13328 B

    const int t  = threadIdx.x;
    const int b  = blockIdx.z;
    const int g  = blockIdx.y;
    const int th = blockIdx.x / 7, tw = blockIdx.x % 7;
    const int h0 = th * 8, w0 = tw * 8;

    // stage lmid [px][c] (stride 72): contiguous-slot b128 copies
#pragma unroll
    for (int i = 0; i < 2; ++i) {
        int s  = t + i * 256;                    // 512 slots
        int px = s >> 3, c8 = s & 7;
        int pix = (h0 + (px >> 3)) * 56 + w0 + (px & 7);
        *(half8t*)&lmid[px * 72 + c8 * 8] =
            *(const half8t*)&mid[(size_t)(b * 3136 + pix) * 64 + c8 * 8];
    }
    // stage lwk [ko][c] (stride 72)
#pragma unroll
    for (int i = 0; i < 2; ++i) {
        int s = t + i * 256;
        int k = s >> 3, c8 = s & 7;
        *(half8t*)&lwk[k * 72 + c8 * 8] = *(const half8t*)&cwb[g * 4096 + s * 8];
    }
    // prefetch x halo (16ch x 14x14 = 3136) into registers
    float rv[13];
#pragma unroll
    for (int i = 0; i < 13; ++i) {
        int idx = t + i * 256;
        float v = 0.f;
        if (idx < 3136) {
            int ch = idx / 196, r = idx % 196;
            int rr = r / 14, col = r % 14;
            int gh = h0 + rr - 3, gw = w0 + col - 3;
            if (gh >= 0 && gh < 56 && gw >= 0 && gw < 56)
                v = x[(b * 256 + g * 16 + ch) * 3136 + gh * 56 + gw];
        }
        rv[i] = v;
    }
    __syncthreads();

    // MFMA GEMM: D[ko][px] = sum_c W[ko][c] * M[c][px]; wave w -> ko rows 16w..
    {
        const int lane = t & 63, wvid = t >> 6;
        const int mrow = lane & 15, quad = lane >> 4;
        half8t a0 = *(const half8t*)&lwk[(wvid * 16 + mrow) * 72 + quad * 8];
        half8t a1 = *(const half8t*)&lwk[(wvid * 16 + mrow) * 72 + quad * 8 + 32];
        float bias[4];
        int   kor[4];
#pragma unroll
        for (int i = 0; i < 4; ++i) {
            kor[i]  = wvid * 16 + quad * 4 + i;
            bias[i] = (kor[i] < 49) ? cb[g * 49 + kor[i]] : 0.f;
        }
#pragma unroll
        for (int pt = 0; pt < 4; ++pt) {
            half8t b0 = *(const half8t*)&lmid[(pt * 16 + mrow) * 72 + quad * 8];
            half8t b1 = *(const half8t*)&lmid[(pt * 16 + mrow) * 72 + quad * 8 + 32];
            floatx4 acc = {0.f, 0.f, 0.f, 0.f};
            acc = __builtin_amdgcn_mfma_f32_16x16x32_f16(a0, b0, acc, 0, 0, 0);
            acc = __builtin_amdgcn_mfma_f32_16x16x32_f16(a1, b1, acc, 0, 0, 0);
#pragma unroll
            for (int i = 0; i < 4; ++i)
                if (kor[i] < 49)
                    lw2[kor[i] * 68 + pt * 16 + mrow] = acc[i] + bias[i];
        }
    }
    __syncthreads();

    // halo regs -> LDS: ch stride 232, row stride 15 (2-way banks in apply)
#pragma unroll
    for (int i = 0; i < 13; ++i) {
        int idx = t + i * 256;
        if (idx < 3136) {
            int ch = idx / 196, r = idx % 196;
            lx[ch * 232 + (r / 14) * 15 + (r % 14)] = rv[i];
        }
    }
    __syncthreads();

    // apply: thread = (cc = t>>4, 4 consecutive out px), fp32
    const int cc = t >> 4, pxt = t & 15;
    const int sh = pxt >> 1, sw4 = (pxt & 1) * 4;
    float a0 = 0.f, a1 = 0.f, a2 = 0.f, a3 = 0.f;
#pragma unroll
    for (int kh = 0; kh < 7; ++kh) {
        float xr[10];
        const int base = cc * 232 + (sh + kh) * 15 + sw4;
#pragma unroll
        for (int j = 0; j < 10; ++j) xr[j] = lx[base + j];
#pragma unroll
        for (int kw = 0; kw < 7; ++kw) {
            const float4 wv = *(const float4*)&lw2[(kh * 7 + kw) * 68 + pxt * 4];
            a0 = fmaf(wv.x, xr[kw + 0], a0);
            a1 = fmaf(wv.y, xr[kw + 1], a1);
            a2 = fmaf(wv.z, xr[kw + 2], a2);
            a3 = fmaf(wv.w, xr[kw + 3], a3);
        }
    }
    *(float4*)&out[(b * 256 + g * 16 + cc) * 3136 + (h0 + sh) * 56 + w0 + sw4] =
        make_float4(a0, a1, a2, a3);
}

extern "C" void kernel_launch(void* const* d_in, const int* in_sizes, int n_in,
                              void* d_out, int out_size, void* d_ws, size_t ws_size,
                              hipStream_t stream) {
    const float* x     = (const float*)d_in[0];
    const float* w1    = (const float*)d_in[1];
    const float* gamma = (const float*)d_in[2];
    const float* beta  = (const float*)d_in[3];
    const float* mean  = (const float*)d_in[4];
    const float* var   = (const float*)d_in[5];
    const float* cw    = (const float*)d_in[6];
    const float* cb    = (const float*)d_in[7];
    float* out = (float*)d_out;

    unsigned char* ws = (unsigned char*)d_ws;
    __fp16* mid  = (__fp16*)(ws);             // 1605632 B
    __fp16* w1fh = (__fp16*)(ws + 1605632);   // 32768 B
    float*  b1f  = (float*)(ws + 1638400);    // 256 B
    __fp16* cwb  = (__fp16*)(ws + 1638656);   // 131072 B

    k0_setup<<<dim3(64), 256, 0, stream>>>(w1, gamma, beta, mean, var, cw,
                                           w1fh, b1f, cwb);
    k1_conv1<<<dim3(49, 4), 256, 0, stream>>>(x, w1fh, b1f, mid);
    k23_fused<<<dim3(49, 16, 4), 256, 0, stream>>>(x, mid, cwb, cb, out);
}